// Round 3
// baseline (782.966 us; speedup 1.0000x reference)
//
#include <hip/hip_runtime.h>
#include <math.h>

// Problem constants
#define NTOK 16384   // B*L
#define LSEQ 4096
#define BATCH 4
#define DDIM 512
#define PDIM 128
#define VDIM 8
#define PI_F 3.14159265358979323846f

// scan chunking
#define NC2 64            // chunks for (b,d) scans, chunk len 64
#define CL2 64
#define NC3 128           // chunks for kv scan, chunk len 32
#define CL3 32

typedef __attribute__((ext_vector_type(8))) short bfrag8;
typedef __attribute__((ext_vector_type(4))) float facc4;

__device__ __forceinline__ float sigmoid_(float v) { return 1.0f / (1.0f + __expf(-v)); }
__device__ __forceinline__ float tanh_(float x) {
    float e = __expf(-2.0f * fabsf(x));
    float t = (1.0f - e) / (1.0f + e);
    return copysignf(t, x);
}
__device__ __forceinline__ float gelu_(float v) {
    float u = 0.7978845608028654f * (v + 0.044715f * v * v * v);
    return 0.5f * v * (1.0f + tanh_(u));
}

// bf16 helpers (raw ushort storage, RNE rounding)
__device__ __forceinline__ unsigned short f2bf(float f) {
    unsigned int u = __builtin_bit_cast(unsigned int, f);
    u += 0x7fffu + ((u >> 16) & 1u);
    return (unsigned short)(u >> 16);
}
__device__ __forceinline__ float bf2f(unsigned short h) {
    return __builtin_bit_cast(float, ((unsigned int)h) << 16);
}
__device__ __forceinline__ float bflo(unsigned int w) { return __builtin_bit_cast(float, w << 16); }
__device__ __forceinline__ float bfhi(unsigned int w) { return __builtin_bit_cast(float, w & 0xffff0000u); }

// async global->LDS, 16B per lane
__device__ __forceinline__ void async16(const unsigned short* g, unsigned short* l) {
    __builtin_amdgcn_global_load_lds(
        (const __attribute__((address_space(1))) unsigned int*)g,
        (__attribute__((address_space(3))) unsigned int*)l, 16, 0, 0);
}

// ---------------------------------------------------------------------------
// bf16 MFMA GEMM, 128x128 tile, BK=32, 4 waves.
// LDS layout [kchunk][row][8] -> conflict-free ds_read_b128.
// 1D grid with XCD swizzle: xcd=id&7 owns nrt/8 row tiles, iterates cols.
// modes: 0 bf16 out; 1 gelu->bf16; 2 fused v/m/q/ke(+phases); 3 phases out;
//        4 fp32 out + residual.
// ---------------------------------------------------------------------------
__global__ __launch_bounds__(256) void gemm_bf16(
    const unsigned short* __restrict__ A, int ldA,
    const unsigned short* __restrict__ Wt,
    const float* __restrict__ bias, int K,
    int nct, int nrt, int mode,
    unsigned short* __restrict__ Ob, int ldC, int colOff,
    float* __restrict__ Of, const float* __restrict__ res,
    unsigned short* __restrict__ X0, unsigned short* __restrict__ X1,
    unsigned short* __restrict__ X2, unsigned short* __restrict__ X3)
{
    __shared__ unsigned short Asm[4096];   // [kq][128][8]
    __shared__ unsigned short Bsm[4096];
    const int tid = threadIdx.x;
    const int lane = tid & 63;
    const int wv = tid >> 6;
    const int wm = wv & 1, wn = wv >> 1;
    const int quad = lane >> 4, cc = lane & 15;

    // XCD-aware block swizzle
    int id = blockIdx.x;
    int xcd = id & 7;
    int per = id >> 3;
    int ct = per % nct;
    int rt = xcd * (nrt >> 3) + per / nct;
    const int row0 = rt << 7;
    const int col0 = ct << 7;

    facc4 acc[4][4];
#pragma unroll
    for (int i = 0; i < 4; ++i)
#pragma unroll
        for (int j = 0; j < 4; ++j) acc[i][j] = (facc4){0.f, 0.f, 0.f, 0.f};

    for (int k0 = 0; k0 < K; k0 += 32) {
        __syncthreads();
        {
            // wave wv stages k-chunk wv for rows lane and lane+64
            const unsigned short* ga0 = A + (size_t)(row0 + lane) * ldA + k0 + wv * 8;
            const unsigned short* ga1 = A + (size_t)(row0 + 64 + lane) * ldA + k0 + wv * 8;
            async16(ga0, &Asm[(wv * 128 + lane) * 8]);
            async16(ga1, &Asm[(wv * 128 + 64 + lane) * 8]);
            const unsigned short* gb0 = Wt + (size_t)(col0 + lane) * K + k0 + wv * 8;
            const unsigned short* gb1 = Wt + (size_t)(col0 + 64 + lane) * K + k0 + wv * 8;
            async16(gb0, &Bsm[(wv * 128 + lane) * 8]);
            async16(gb1, &Bsm[(wv * 128 + 64 + lane) * 8]);
        }
        __syncthreads();
        bfrag8 afr[4], bfr[4];
#pragma unroll
        for (int mt = 0; mt < 4; ++mt)
            afr[mt] = *(const bfrag8*)&Asm[(quad * 128 + wm * 64 + mt * 16 + cc) * 8];
#pragma unroll
        for (int nt = 0; nt < 4; ++nt)
            bfr[nt] = *(const bfrag8*)&Bsm[(quad * 128 + wn * 64 + nt * 16 + cc) * 8];
#pragma unroll
        for (int mt = 0; mt < 4; ++mt)
#pragma unroll
            for (int nt = 0; nt < 4; ++nt)
                acc[mt][nt] = __builtin_amdgcn_mfma_f32_16x16x32_bf16(
                    afr[mt], bfr[nt], acc[mt][nt], 0, 0, 0);
    }

#pragma unroll
    for (int nt = 0; nt < 4; ++nt) {
        int col = col0 + wn * 64 + nt * 16 + cc;
        float bvv = bias[col];
#pragma unroll
        for (int mt = 0; mt < 4; ++mt) {
            int rowb = row0 + wm * 64 + mt * 16 + quad * 4;
#pragma unroll
            for (int r = 0; r < 4; ++r) {
                float v = acc[mt][nt][r] + bvv;
                size_t row = (size_t)(rowb + r);
                if (mode == 0) {
                    Ob[row * ldC + colOff + col] = f2bf(v);
                } else if (mode == 1) {
                    Ob[row * ldC + colOff + col] = f2bf(gelu_(v));
                } else if (mode == 2) {
                    if (col < 512)       Ob[row * 512 + col] = f2bf(v);
                    else if (col < 1024) X0[row * 512 + col - 512] = f2bf(v);
                    else if (col < 1536) X1[row * 512 + col - 1024] = f2bf(v);
                    else {
                        int c = col - 1536;
                        float ph = tanh_(v) * PI_F;
                        X2[row * 128 + c] = f2bf(__cosf(ph));
                        X3[row * 128 + c] = f2bf(__sinf(ph));
                    }
                } else if (mode == 3) {
                    float ph = tanh_(v) * PI_F;
                    X2[row * 128 + col] = f2bf(__cosf(ph));
                    X3[row * 128 + col] = f2bf(__sinf(ph));
                } else {   // mode 4: fp32 + residual
                    Of[row * 512 + col] = v + res[row * 512 + col];
                }
            }
        }
    }
}

// ---------------------------------------------------------------------------
// weight convert+transpose: Wt[n*K+k] = bf16(W[k*N+n]). Grid (N/32, K/32).
// ---------------------------------------------------------------------------
__global__ __launch_bounds__(256) void k_wcvt(const float* __restrict__ W, int K, int N,
                                              unsigned short* __restrict__ Wt)
{
    __shared__ float t[32][33];
    int bx = blockIdx.x, by = blockIdx.y;
    int tid = threadIdx.x;
    int tx = tid & 31, ty = tid >> 5;   // ty 0..7
#pragma unroll
    for (int r = 0; r < 4; ++r) {
        int k = by * 32 + ty + r * 8;
        t[ty + r * 8][tx] = W[(size_t)k * N + bx * 32 + tx];
    }
    __syncthreads();
#pragma unroll
    for (int r = 0; r < 4; ++r) {
        int n = bx * 32 + ty + r * 8;
        Wt[(size_t)n * K + by * 32 + tx] = f2bf(t[tx][ty + r * 8]);
    }
}

// bias concat for fused vmqke GEMM
__global__ void k_bcat(const float* __restrict__ a, const float* __restrict__ b,
                       const float* __restrict__ c, const float* __restrict__ d,
                       float* __restrict__ o)
{
    int i = blockIdx.x * 256 + threadIdx.x;
    if (i >= 1664) return;
    float v = (i < 512) ? a[i] : (i < 1024) ? b[i - 512] : (i < 1536) ? c[i - 1024] : d[i - 1536];
    o[i] = v;
}

// x (N x 512 fp32) -> XCAT left half (N x 1024 bf16)
__global__ void k_xcvt(const float* __restrict__ x, unsigned short* __restrict__ xcat)
{
    int g = blockIdx.x * 256 + threadIdx.x;
    int c = g & 511, r = g >> 9;
    xcat[(size_t)r * 1024 + c] = f2bf(x[g]);
}

// cos/sin of pos_phases -> bf16 tables
__global__ void k_phi(const float* __restrict__ pp, unsigned short* __restrict__ cphi,
                      unsigned short* __restrict__ sphi, int n)
{
    int i = blockIdx.x * 256 + threadIdx.x;
    if (i < n) {
        float p = pp[i];
        cphi[i] = f2bf(__cosf(p));
        sphi[i] = f2bf(__sinf(p));
    }
}

// ---------------------------------------------------------------------------
// fused g_lin + values: wave per row.
// ---------------------------------------------------------------------------
__global__ __launch_bounds__(256) void k_vg(const float* __restrict__ x,
                                            const float* __restrict__ wve,
                                            const float* __restrict__ bve,
                                            const float* __restrict__ wg,
                                            const float* __restrict__ bg,
                                            float* __restrict__ gv,
                                            float* __restrict__ glin)
{
    int wid = threadIdx.x >> 6, lane = threadIdx.x & 63;
    int row = blockIdx.x * 4 + wid;
    const float4* xr = (const float4*)(x + (size_t)row * DDIM);
    float4 a0 = xr[lane * 2], a1 = xr[lane * 2 + 1];
    float xs[8] = {a0.x, a0.y, a0.z, a0.w, a1.x, a1.y, a1.z, a1.w};
    float acc[8] = {0, 0, 0, 0, 0, 0, 0, 0};
    float accg = 0.f;
#pragma unroll
    for (int j = 0; j < 8; ++j) {
        int k = lane * 8 + j;
        const float4* wr = (const float4*)(wve + (size_t)k * 8);
        float4 w0 = wr[0], w1 = wr[1];
        acc[0] += xs[j] * w0.x; acc[1] += xs[j] * w0.y;
        acc[2] += xs[j] * w0.z; acc[3] += xs[j] * w0.w;
        acc[4] += xs[j] * w1.x; acc[5] += xs[j] * w1.y;
        acc[6] += xs[j] * w1.z; acc[7] += xs[j] * w1.w;
        accg += xs[j] * wg[k];
    }
#pragma unroll
    for (int off = 32; off >= 1; off >>= 1) {
#pragma unroll
        for (int m = 0; m < 8; ++m) acc[m] += __shfl_down(acc[m], off, 64);
        accg += __shfl_down(accg, off, 64);
    }
    if (lane == 0) {
        float gl = accg + bg[0];
        glin[row] = gl;
        float sg = sigmoid_(gl);
#pragma unroll
        for (int m = 0; m < 8; ++m) gv[(size_t)row * 8 + m] = (acc[m] + bve[m]) * sg;
    }
}

// ---------------------------------------------------------------------------
// scan family 1 (3 passes). bf16 v1/mlin/qlin + bf16 phi tables.
// ---------------------------------------------------------------------------
__global__ __launch_bounds__(256) void k_scan1a(
    const unsigned short* __restrict__ v1, const unsigned short* __restrict__ mlin,
    const float* __restrict__ x,
    const unsigned short* __restrict__ cphi, const unsigned short* __restrict__ sphi,
    const float* __restrict__ msp, float* __restrict__ sum2)
{
    int g = blockIdx.x * 256 + threadIdx.x;   // B*NC2*D = 131072
    int d = g & 511;
    int rest = g >> 9;
    int chunk = rest & (NC2 - 1);
    int b = rest >> 6;
    float msabs = fabsf(msp[0]);
    size_t base = ((size_t)b * LSEQ + chunk * CL2) * DDIM + d;
    size_t pbase = ((size_t)chunk * CL2) * DDIM + d;
    float ac = 0.f, as = 0.f, am = 0.f, ax = 0.f;
    for (int i = 0; i < CL2; ++i) {
        float ml = bf2f(mlin[base]), vv = bf2f(v1[base]), xv = x[base];
        float cp = bf2f(cphi[pbase]), sp = bf2f(sphi[pbase]);
        float mag = msabs * sigmoid_(ml);
        float wv = mag * vv;
        ac += wv * cp; as += wv * sp; am += mag; ax += xv;
        base += DDIM; pbase += DDIM;
    }
    int col = (b * DDIM + d) * NC2 + chunk;
    sum2[0 * 131072 + col] = ac;
    sum2[1 * 131072 + col] = as;
    sum2[2 * 131072 + col] = am;
    sum2[3 * 131072 + col] = ax;
}

__global__ __launch_bounds__(256) void k_scan1b(float* __restrict__ sum2)
{
    int g = blockIdx.x * 256 + threadIdx.x;   // 8192 rows of NC2
    float* p = sum2 + (size_t)g * NC2;
    float run = 0.f;
    for (int i = 0; i < NC2; ++i) { float t = p[i]; p[i] = run; run += t; }
}

__global__ __launch_bounds__(256) void k_scan1c(
    const unsigned short* __restrict__ v1, const unsigned short* __restrict__ mlin,
    const unsigned short* __restrict__ qlin, const float* __restrict__ x,
    const unsigned short* __restrict__ cphi, const unsigned short* __restrict__ sphi,
    const float* __restrict__ msp, const float* __restrict__ sum2,
    unsigned short* __restrict__ pret, unsigned short* __restrict__ xcat)
{
    int g = blockIdx.x * 256 + threadIdx.x;
    int d = g & 511;
    int rest = g >> 9;
    int chunk = rest & (NC2 - 1);
    int b = rest >> 6;
    float msabs = fabsf(msp[0]);
    int col = (b * DDIM + d) * NC2 + chunk;
    float ac = sum2[col];
    float as = sum2[131072 + col];
    float am = sum2[2 * 131072 + col];
    float ax = sum2[3 * 131072 + col];
    size_t base = ((size_t)b * LSEQ + chunk * CL2) * DDIM + d;
    size_t pbase = ((size_t)chunk * CL2) * DDIM + d;
    int l = chunk * CL2;
    const float rsd = 0.04419417382415922f;   // 1/sqrt(512)
    for (int i = 0; i < CL2; ++i, ++l) {
        float ml = bf2f(mlin[base]), vv = bf2f(v1[base]), xv = x[base];
        float q = bf2f(qlin[base]);
        float cp = bf2f(cphi[pbase]), sp = bf2f(sphi[pbase]);
        float mag = msabs * sigmoid_(ml);
        float wv = mag * vv;
        ac += wv * cp; as += wv * sp; am += mag; ax += xv;
        float inv = rsqrtf(am + 1e-8f);
        float mc = ac * inv, msn = as * inv;
        float cq = __cosf(q), sq = __sinf(q);
        float cpq = cp * cq - sp * sq;
        float spq = sp * cq + cp * sq;
        pret[base] = f2bf((mc * cpq + msn * spq) * rsd);
        size_t row = (size_t)b * LSEQ + l;
        xcat[row * 1024 + 512 + d] = f2bf(ax / (float)(l + 1));
        base += DDIM; pbase += DDIM;
    }
}

// ---------------------------------------------------------------------------
// gate cumsum per batch
// ---------------------------------------------------------------------------
__global__ __launch_bounds__(1024) void k_gatescan(const float* __restrict__ glin,
                                                   float* __restrict__ gcum)
{
    __shared__ float s[1024];
    int b = blockIdx.x, tid = threadIdx.x;
    const float* gp = glin + (size_t)b * LSEQ + tid * 4;
    float e0 = sigmoid_(gp[0]);
    float e1 = sigmoid_(gp[1]);
    float e2 = sigmoid_(gp[2]);
    float e3 = sigmoid_(gp[3]);
    float l0 = e0, l1 = l0 + e1, l2 = l1 + e2, l3 = l2 + e3;
    s[tid] = l3;
    __syncthreads();
    for (int off = 1; off < 1024; off <<= 1) {
        float t = (tid >= off) ? s[tid - off] : 0.0f;
        __syncthreads();
        s[tid] += t;
        __syncthreads();
    }
    float excl = s[tid] - l3;
    float* out = gcum + (size_t)b * LSEQ + tid * 4;
    out[0] = excl + l0; out[1] = excl + l1; out[2] = excl + l2; out[3] = excl + l3;
}

// ---------------------------------------------------------------------------
// kv scan
// ---------------------------------------------------------------------------
__device__ __forceinline__ size_t kv_sum_idx(int b, int p, int v) {
    return ((((size_t)b * PDIM + p) * VDIM + v) * 2) * NC3;
}

__global__ __launch_bounds__(256) void k_kv1(const unsigned short* __restrict__ csp,
                                             const unsigned short* __restrict__ ssp,
                                             const float* __restrict__ gv,
                                             float* __restrict__ sum3)
{
    int blk = blockIdx.x;                 // B*NC3 = 512
    int chunk = blk & (NC3 - 1), b = blk >> 7;
    int tid = threadIdx.x;
    int w = tid >> 6, lane = tid & 63;
    int v = 2 * w + (lane & 1);
    int pq = lane >> 1;                   // 0..31
    float sc[4] = {0, 0, 0, 0}, ss[4] = {0, 0, 0, 0};
    const uint2* c2p = (const uint2*)csp;
    const uint2* s2p = (const uint2*)ssp;
    int t = b * LSEQ + chunk * CL3;
    for (int i = 0; i < CL3; ++i, ++t) {
        uint2 cu = c2p[(size_t)t * 32 + pq];
        uint2 su = s2p[(size_t)t * 32 + pq];
        float g = gv[(size_t)t * VDIM + v];
        sc[0] += bflo(cu.x) * g; sc[1] += bfhi(cu.x) * g;
        sc[2] += bflo(cu.y) * g; sc[3] += bfhi(cu.y) * g;
        ss[0] += bflo(su.x) * g; ss[1] += bfhi(su.x) * g;
        ss[2] += bflo(su.y) * g; ss[3] += bfhi(su.y) * g;
    }
#pragma unroll
    for (int j = 0; j < 4; ++j) {
        size_t base = kv_sum_idx(b, pq * 4 + j, v) + chunk;
        sum3[base] = sc[j];
        sum3[base + NC3] = ss[j];
    }
}

__global__ __launch_bounds__(256) void k_kv2(float* __restrict__ sum3)
{
    int g = blockIdx.x * 256 + threadIdx.x;   // 8192 rows
    float* p = sum3 + (size_t)g * NC3;
    float run = 0.f;
    for (int i = 0; i < NC3; ++i) { float t = p[i]; p[i] = run; run += t; }
}

__global__ __launch_bounds__(256) void k_kv3(const unsigned short* __restrict__ csp,
                                             const unsigned short* __restrict__ ssp,
                                             const unsigned short* __restrict__ cqp,
                                             const unsigned short* __restrict__ sqp,
                                             const float* __restrict__ gv,
                                             const float* __restrict__ gcum,
                                             const float* __restrict__ sum3,
                                             float* __restrict__ kvr)
{
    int blk = blockIdx.x;
    int chunk = blk & (NC3 - 1), b = blk >> 7;
    int tid = threadIdx.x;
    int w = tid >> 6, lane = tid & 63;
    int v = 2 * w + (lane & 1);
    int pq = lane >> 1;
    float sc[4], ss[4];
#pragma unroll
    for (int j = 0; j < 4; ++j) {
        size_t base = kv_sum_idx(b, pq * 4 + j, v) + chunk;
        sc[j] = sum3[base];
        ss[j] = sum3[base + NC3];
    }
    const uint2* c2p = (const uint2*)csp;
    const uint2* s2p = (const uint2*)ssp;
    const uint2* cq2p = (const uint2*)cqp;
    const uint2* sq2p = (const uint2*)sqp;
    const float rsp = 0.08838834764831845f;   // 1/sqrt(128)
    int t = b * LSEQ + chunk * CL3;
    for (int i = 0; i < CL3; ++i, ++t) {
        uint2 cu = c2p[(size_t)t * 32 + pq];
        uint2 su = s2p[(size_t)t * 32 + pq];
        float g = gv[(size_t)t * VDIM + v];
        sc[0] += bflo(cu.x) * g; sc[1] += bfhi(cu.x) * g;
        sc[2] += bflo(cu.y) * g; sc[3] += bfhi(cu.y) * g;
        ss[0] += bflo(su.x) * g; ss[1] += bfhi(su.x) * g;
        ss[2] += bflo(su.y) * g; ss[3] += bfhi(su.y) * g;
        uint2 qcu = cq2p[(size_t)t * 32 + pq];
        uint2 qsu = sq2p[(size_t)t * 32 + pq];
        float part = bflo(qcu.x) * sc[0] + bfhi(qcu.x) * sc[1]
                   + bflo(qcu.y) * sc[2] + bfhi(qcu.y) * sc[3]
                   + bflo(qsu.x) * ss[0] + bfhi(qsu.x) * ss[1]
                   + bflo(qsu.y) * ss[2] + bfhi(qsu.y) * ss[3];
        part += __shfl_down(part, 32, 64);
        part += __shfl_down(part, 16, 64);
        part += __shfl_down(part, 8, 64);
        part += __shfl_down(part, 4, 64);
        part += __shfl_down(part, 2, 64);
        if (lane < 2) {
            float gc = gcum[t];
            float scale = rsqrtf(fmaxf(gc, 1.0f)) * rsp;
            kvr[(size_t)t * VDIM + v] = part * scale;
        }
    }
}

// ---------------------------------------------------------------------------
// fused kv_out + LayerNorm. Wave per row; left lanes read comb (pos_out),
// right lanes compute kvr@w_kv on the fly (w_kv staged in LDS).
// ---------------------------------------------------------------------------
__global__ __launch_bounds__(256) void k_lnkv(unsigned short* __restrict__ comb,
                                              const float* __restrict__ kvr,
                                              const float* __restrict__ wkv,
                                              const float* __restrict__ bkv,
                                              const float* __restrict__ gam,
                                              const float* __restrict__ bet)
{
    __shared__ float wks[4096];
    __shared__ float bks[512];
    int tid = threadIdx.x;
    for (int i = tid; i < 4096; i += 256) wks[i] = wkv[i];
    for (int i = tid; i < 512; i += 256) bks[i] = bkv[i];
    __syncthreads();
    int wid = tid >> 6, lane = tid & 63;
    int row = blockIdx.x * 4 + wid;
    unsigned short* rp = comb + (size_t)row * 1024;
    float v[16];
    if (lane < 32) {
        uint4 u0 = *(uint4*)(rp + lane * 16);
        uint4 u1 = *(uint4*)(rp + lane * 16 + 8);
        unsigned int uu[8] = {u0.x, u0.y, u0.z, u0.w, u1.x, u1.y, u1.z, u1.w};
#pragma unroll
        for (int j = 0; j < 8; ++j) { v[2 * j] = bflo(uu[j]); v[2 * j + 1] = bfhi(uu[j]); }
    } else {
        int c0 = (lane - 32) * 16;
        const float4* kr = (const float4*)(kvr + (size_t)row * 8);
        float4 k0 = kr[0], k1 = kr[1];
        float kk[8] = {k0.x, k0.y, k0.z, k0.w, k1.x, k1.y, k1.z, k1.w};
#pragma unroll
        for (int j = 0; j < 16; ++j) {
            int c = c0 + j;
            float a = bks[c];
#pragma unroll
            for (int k = 0; k < 8; ++k) a += kk[k] * wks[k * 512 + c];
            v[j] = a;
        }
    }
    float s = 0.f, s2 = 0.f;
#pragma unroll
    for (int j = 0; j < 16; ++j) { s += v[j]; s2 += v[j] * v[j]; }
    for (int m = 32; m >= 1; m >>= 1) {
        s += __shfl_xor(s, m, 64);
        s2 += __shfl_xor(s2, m, 64);
    }
    float mu = s * (1.0f / 1024.0f);
    float var = s2 * (1.0f / 1024.0f) - mu * mu;
    float inv = rsqrtf(var + 1e-5f);
    int cbase = lane * 16;
    unsigned int ou[8];
#pragma unroll
    for (int j = 0; j < 8; ++j) {
        float g0 = gam[cbase + 2 * j], g1 = gam[cbase + 2 * j + 1];
        float b0 = bet[cbase + 2 * j], b1 = bet[cbase + 2 * j + 1];
        float o0 = (v[2 * j] - mu) * inv * g0 + b0;
        float o1 = (v[2 * j + 1] - mu) * inv * g1 + b1;
        ou[j] = (unsigned int)f2bf(o0) | ((unsigned int)f2bf(o1) << 16);
    }
    *(uint4*)(rp + cbase) = make_uint4(ou[0], ou[1], ou[2], ou[3]);
    *(uint4*)(rp + cbase + 8) = make_uint4(ou[4], ou[5], ou[6], ou[7]);
}

// ---------------------------------------------------------------------------
extern "C" void kernel_launch(void* const* d_in, const int* in_sizes, int n_in,
                              void* d_out, int out_size, void* d_ws, size_t ws_size,
                              hipStream_t stream)
{
    const float* x    = (const float*)d_in[0];
    const float* pp   = (const float*)d_in[1];
    const float* msp  = (const float*)d_in[2];
    const float* w_v  = (const float*)d_in[3];
    const float* b_v  = (const float*)d_in[4];
    const float* w_o  = (const float*)d_in[5];
    const float* b_o  = (const float*)d_in[6];
    const float* w_m  = (const float*)d_in[7];
    const float* b_m  = (const float*)d_in[8];
    const float* w_q  = (const float*)d_in[9];
    const float* b_q  = (const float*)d_in[10];
    const float* w_ke = (const float*)d_in[11];
    const float* b_ke = (const float*)d_in[12];
    const float* w_ve = (const float*)d_in[13];
    const float* b_ve = (const float*)d_in[14];
    const float* w_s1 = (const float*)d_in[15];
    const float* b_s1 = (const float*)d_in[16];
    const float* w_s2 = (const float*)d_in[17];
    const float* b_s2 = (const float*)d_in[18];
    const float* w_g  = (const float*)d_in[19];
    const float* b_g  = (const float*)d_in[20];
    const float* w_kv = (const float*)d_in[21];
    const float* b_kv = (const float*)d_in[22];
    const float* ln_g = (const float*)d_in[23];
    const float* ln_b = (const float*)d_in[24];
    const float* w_t1 = (const float*)d_in[25];
    const float* b_t1 = (const float*)d_in[26];
    const float* w_t2 = (const float*)d_in[27];
    const float* b_t2 = (const float*)d_in[28];
    float* out = (float*)d_out;
    float* ws = (float*)d_ws;
    (void)ws_size; (void)n_in; (void)in_sizes; (void)out_size;

    // ---- workspace layout (float offsets); ~157 MB
    unsigned short* V1bf   = (unsigned short*)(ws);              // N*512 bf16 (4M f)
    unsigned short* MLINbf = (unsigned short*)(ws + 4194304);    // N*512 bf16
    unsigned short* QLINbf = (unsigned short*)(ws + 8388608);    // N*512 bf16
    unsigned short* CQP    = (unsigned short*)(ws + 12582912);   // N*128 bf16 (1M f)
    unsigned short* SQP    = (unsigned short*)(ws + 13631488);
    unsigned short* CSP    = (unsigned short*)(ws + 14680064);
    unsigned short* SSP    = (unsigned short*)(ws + 15728640);
    unsigned short* HSbf   = (unsigned short*)(ws + 16777216);   // N*512 bf16
    unsigned short* PRETbf = (unsigned short*)(ws + 20971520);   // N*512 bf16
    unsigned short* CPHIbf = (unsigned short*)(ws + 25165824);   // L*512 bf16 (1M f)
    unsigned short* SPHIbf = (unsigned short*)(ws + 26214400);
    float* GVb   = ws + 27262976;                                // N*8
    float* GLINb = ws + 27394048;                                // N
    float* GCUMb = ws + 27410432;                                // N
    float* SUM2b = ws + 27426816;                                // 524288
    float* SUM3b = ws + 27951104;                                // 1048576
    float* KVRb  = ws + 28999680;                                // N*8
    unsigned short* XCAT   = (unsigned short*)(ws + 29130752);   // N*1024 bf16 (8M f)
    unsigned short* COMBbf = XCAT;                               // alias (x/ctx dead after s1)
    unsigned short* HTbf   = (unsigned short*)(ws);              // alias V1+MLIN (dead after scan1c)
    unsigned short* WtF    = (unsigned short*)(ws + 37519360);   // 1664x512 bf16
    unsigned short* ws1_t  = (unsigned short*)(ws + 37945344);   // 512x1024
    unsigned short* ws2_t  = (unsigned short*)(ws + 38207488);   // 128x512
    unsigned short* wo_t   = (unsigned short*)(ws + 38240256);   // 512x512
    unsigned short* wt1_t  = (unsigned short*)(ws + 38371328);   // 1024x1024
    unsigned short* wt2_t  = (unsigned short*)(ws + 38895616);   // 512x1024
    float* BIASF           = ws + 39157760;                      // 1664

    // 1. conversions + tables
    k_phi<<<8192, 256, 0, stream>>>(pp, CPHIbf, SPHIbf, 2097152);
    k_xcvt<<<32768, 256, 0, stream>>>(x, XCAT);
    k_bcat<<<7, 256, 0, stream>>>(b_v, b_m, b_q, b_ke, BIASF);
    k_wcvt<<<dim3(16, 16), 256, 0, stream>>>(w_v, 512, 512, WtF);
    k_wcvt<<<dim3(16, 16), 256, 0, stream>>>(w_m, 512, 512, WtF + 512 * 512);
    k_wcvt<<<dim3(16, 16), 256, 0, stream>>>(w_q, 512, 512, WtF + 1024 * 512);
    k_wcvt<<<dim3(4, 16), 256, 0, stream>>>(w_ke, 512, 128, WtF + 1536 * 512);
    k_wcvt<<<dim3(16, 32), 256, 0, stream>>>(w_s1, 1024, 512, ws1_t);
    k_wcvt<<<dim3(4, 16), 256, 0, stream>>>(w_s2, 512, 128, ws2_t);
    k_wcvt<<<dim3(16, 16), 256, 0, stream>>>(w_o, 512, 512, wo_t);
    k_wcvt<<<dim3(32, 32), 256, 0, stream>>>(w_t1, 1024, 1024, wt1_t);
    k_wcvt<<<dim3(16, 32), 256, 0, stream>>>(w_t2, 1024, 512, wt2_t);

    // 2. fused v/m/q/ke GEMM (+ query-phase epilogue) and small projections
    gemm_bf16<<<1664, 256, 0, stream>>>(XCAT, 1024, WtF, BIASF, 512, 13, 128, 2,
                                        V1bf, 512, 0, nullptr, nullptr,
                                        MLINbf, QLINbf, CQP, SQP);
    k_vg<<<4096, 256, 0, stream>>>(x, w_ve, b_ve, w_g, b_g, GVb, GLINb);

    // 3. (b,d) scans -> pos_ret, context_avg
    k_scan1a<<<512, 256, 0, stream>>>(V1bf, MLINbf, x, CPHIbf, SPHIbf, msp, SUM2b);
    k_scan1b<<<32, 256, 0, stream>>>(SUM2b);
    k_scan1c<<<512, 256, 0, stream>>>(V1bf, MLINbf, QLINbf, x, CPHIbf, SPHIbf, msp, SUM2b, PRETbf, XCAT);

    // 4. storage-key branch: s1 -> gelu -> s2 -> storage phases (epilogue)
    gemm_bf16<<<512, 256, 0, stream>>>(XCAT, 1024, ws1_t, b_s1, 1024, 4, 128, 1,
                                       HSbf, 512, 0, nullptr, nullptr,
                                       nullptr, nullptr, nullptr, nullptr);
    gemm_bf16<<<128, 256, 0, stream>>>(HSbf, 512, ws2_t, b_s2, 512, 1, 128, 3,
                                       nullptr, 128, 0, nullptr, nullptr,
                                       nullptr, nullptr, CSP, SSP);
    k_gatescan<<<4, 1024, 0, stream>>>(GLINb, GCUMb);

    // 5. kv scan -> kv_retrieved
    k_kv1<<<512, 256, 0, stream>>>(CSP, SSP, GVb, SUM3b);
    k_kv2<<<32, 256, 0, stream>>>(SUM3b);
    k_kv3<<<512, 256, 0, stream>>>(CSP, SSP, CQP, SQP, GVb, GCUMb, SUM3b, KVRb);

    // 6. heads: o-GEMM into comb left; fused kvout+LN; MLP; residual out
    gemm_bf16<<<512, 256, 0, stream>>>(PRETbf, 512, wo_t, b_o, 512, 4, 128, 0,
                                       COMBbf, 1024, 0, nullptr, nullptr,
                                       nullptr, nullptr, nullptr, nullptr);
    k_lnkv<<<4096, 256, 0, stream>>>(COMBbf, KVRb, w_kv, b_kv, ln_g, ln_b);
    gemm_bf16<<<1024, 256, 0, stream>>>(COMBbf, 1024, wt1_t, b_t1, 1024, 8, 128, 1,
                                        HTbf, 1024, 0, nullptr, nullptr,
                                        nullptr, nullptr, nullptr, nullptr);
    gemm_bf16<<<512, 256, 0, stream>>>(HTbf, 1024, wt2_t, b_t2, 1024, 4, 128, 4,
                                       nullptr, 512, 0, out, x,
                                       nullptr, nullptr, nullptr, nullptr);
}

// Round 4
// 687.634 us; speedup vs baseline: 1.1386x; 1.1386x over previous
//
#include <hip/hip_runtime.h>
#include <math.h>

// Problem constants
#define NTOK 16384   // B*L
#define LSEQ 4096
#define BATCH 4
#define DDIM 512
#define PDIM 128
#define VDIM 8
#define PI_F 3.14159265358979323846f

// scan chunking
#define NC2 64            // chunks for (b,d) scans, chunk len 64
#define CL2 64
#define NC3 128           // chunks for kv scan, chunk len 32
#define CL3 32

typedef __attribute__((ext_vector_type(8))) short bfrag8;
typedef __attribute__((ext_vector_type(4))) float facc4;

__device__ __forceinline__ float sigmoid_(float v) { return 1.0f / (1.0f + __expf(-v)); }
__device__ __forceinline__ float tanh_(float x) {
    float e = __expf(-2.0f * fabsf(x));
    float t = (1.0f - e) / (1.0f + e);
    return copysignf(t, x);
}
__device__ __forceinline__ float gelu_(float v) {
    float u = 0.7978845608028654f * (v + 0.044715f * v * v * v);
    return 0.5f * v * (1.0f + tanh_(u));
}

// bf16 helpers (raw ushort storage, RNE rounding)
__device__ __forceinline__ unsigned short f2bf(float f) {
    unsigned int u = __builtin_bit_cast(unsigned int, f);
    u += 0x7fffu + ((u >> 16) & 1u);
    return (unsigned short)(u >> 16);
}
__device__ __forceinline__ float bf2f(unsigned short h) {
    return __builtin_bit_cast(float, ((unsigned int)h) << 16);
}
__device__ __forceinline__ float bflo(unsigned int w) { return __builtin_bit_cast(float, w << 16); }
__device__ __forceinline__ float bfhi(unsigned int w) { return __builtin_bit_cast(float, w & 0xffff0000u); }

// async global->LDS, 16B per lane
__device__ __forceinline__ void async16(const unsigned short* g, unsigned short* l) {
    __builtin_amdgcn_global_load_lds(
        (const __attribute__((address_space(1))) unsigned int*)g,
        (__attribute__((address_space(3))) unsigned int*)l, 16, 0, 0);
}

// ---------------------------------------------------------------------------
// bf16 MFMA GEMM, 128x128 tile, BK=64, 4 waves (2x2), 4x4 16x16x32 MFMA each.
// Staging: coalesced (8 lanes = 128B contiguous per row), LDS [row][64]
// with XOR k-chunk swizzle (chunk kq stored holds global chunk kq^(r&7)) ->
// bank-balanced ds_read_b128 AND full-line global reads.
// 1D grid, XCD swizzle: xcd=id&7 owns nrt/8 row tiles, iterates cols.
// modes: 0 bf16 out; 1 gelu->bf16; 2 fused v/m/q/ke(+query phases);
//        3 storage phases out; 4 fp32 out + residual.
// ---------------------------------------------------------------------------
__global__ __launch_bounds__(256) void gemm_bf16(
    const unsigned short* __restrict__ A, int ldA,
    const unsigned short* __restrict__ Wt,
    const float* __restrict__ bias, int K,
    int nct, int nrt, int mode,
    unsigned short* __restrict__ Ob, int ldC, int colOff,
    float* __restrict__ Of, const float* __restrict__ res,
    unsigned short* __restrict__ X0, unsigned short* __restrict__ X1,
    unsigned short* __restrict__ X2, unsigned short* __restrict__ X3)
{
    __shared__ unsigned short Asm[128 * 64];   // [row][kchunk swizzled]
    __shared__ unsigned short Bsm[128 * 64];
    const int tid = threadIdx.x;
    const int lane = tid & 63;
    const int wv = tid >> 6;
    const int wm = wv & 1, wn = wv >> 1;
    const int quad = lane >> 4, cc = lane & 15;

    // XCD-aware block swizzle
    int id = blockIdx.x;
    int xcd = id & 7;
    int per = id >> 3;
    int ct = per % nct;
    int rt = xcd * (nrt >> 3) + per / nct;
    const int row0 = rt << 7;
    const int col0 = ct << 7;

    facc4 acc[4][4];
#pragma unroll
    for (int i = 0; i < 4; ++i)
#pragma unroll
        for (int j = 0; j < 4; ++j) acc[i][j] = (facc4){0.f, 0.f, 0.f, 0.f};

    for (int k0 = 0; k0 < K; k0 += 64) {
        __syncthreads();
#pragma unroll
        for (int it = 0; it < 4; ++it) {
            int idx = it * 256 + tid;        // 0..1023
            int r = idx >> 3;                // 0..127
            int kq = idx & 7;                // chunk slot
            int kqe = kq ^ (r & 7);          // global chunk fetched into slot kq
            async16(A + (size_t)(row0 + r) * ldA + k0 + kqe * 8, &Asm[idx * 8]);
            async16(Wt + (size_t)(col0 + r) * K + k0 + kqe * 8, &Bsm[idx * 8]);
        }
        __syncthreads();
#pragma unroll
        for (int kc = 0; kc < 2; ++kc) {
            bfrag8 afr[4], bfr[4];
#pragma unroll
            for (int mt = 0; mt < 4; ++mt) {
                int r = wm * 64 + mt * 16 + cc;
                afr[mt] = *(const bfrag8*)&Asm[r * 64 + (((kc * 4 + quad) ^ (cc & 7)) * 8)];
            }
#pragma unroll
            for (int nt = 0; nt < 4; ++nt) {
                int r = wn * 64 + nt * 16 + cc;
                bfr[nt] = *(const bfrag8*)&Bsm[r * 64 + (((kc * 4 + quad) ^ (cc & 7)) * 8)];
            }
#pragma unroll
            for (int mt = 0; mt < 4; ++mt)
#pragma unroll
                for (int nt = 0; nt < 4; ++nt)
                    acc[mt][nt] = __builtin_amdgcn_mfma_f32_16x16x32_bf16(
                        afr[mt], bfr[nt], acc[mt][nt], 0, 0, 0);
        }
    }

#pragma unroll
    for (int nt = 0; nt < 4; ++nt) {
        int col = col0 + wn * 64 + nt * 16 + cc;
        float bvv = bias[col];
#pragma unroll
        for (int mt = 0; mt < 4; ++mt) {
            int rowb = row0 + wm * 64 + mt * 16 + quad * 4;
#pragma unroll
            for (int r = 0; r < 4; ++r) {
                float v = acc[mt][nt][r] + bvv;
                size_t row = (size_t)(rowb + r);
                if (mode == 0) {
                    Ob[row * ldC + colOff + col] = f2bf(v);
                } else if (mode == 1) {
                    Ob[row * ldC + colOff + col] = f2bf(gelu_(v));
                } else if (mode == 2) {
                    if (col < 512)       Ob[row * 512 + col] = f2bf(v);
                    else if (col < 1024) X0[row * 512 + col - 512] = f2bf(v);
                    else if (col < 1536) X1[row * 512 + col - 1024] = f2bf(v);
                    else {
                        int c = col - 1536;
                        float ph = tanh_(v) * PI_F;
                        X2[row * 128 + c] = f2bf(__cosf(ph));
                        X3[row * 128 + c] = f2bf(__sinf(ph));
                    }
                } else if (mode == 3) {
                    float ph = tanh_(v) * PI_F;
                    X2[row * 128 + col] = f2bf(__cosf(ph));
                    X3[row * 128 + col] = f2bf(__sinf(ph));
                } else {   // mode 4: fp32 + residual
                    Of[row * 512 + col] = v + res[row * 512 + col];
                }
            }
        }
    }
}

// ---------------------------------------------------------------------------
// weight convert+transpose: Wt[n*K+k] = bf16(W[k*N+n]). Grid (N/32, K/32).
// ---------------------------------------------------------------------------
__global__ __launch_bounds__(256) void k_wcvt(const float* __restrict__ W, int K, int N,
                                              unsigned short* __restrict__ Wt)
{
    __shared__ float t[32][33];
    int bx = blockIdx.x, by = blockIdx.y;
    int tid = threadIdx.x;
    int tx = tid & 31, ty = tid >> 5;   // ty 0..7
#pragma unroll
    for (int r = 0; r < 4; ++r) {
        int k = by * 32 + ty + r * 8;
        t[ty + r * 8][tx] = W[(size_t)k * N + bx * 32 + tx];
    }
    __syncthreads();
#pragma unroll
    for (int r = 0; r < 4; ++r) {
        int n = bx * 32 + ty + r * 8;
        Wt[(size_t)n * K + by * 32 + tx] = f2bf(t[tx][ty + r * 8]);
    }
}

// bias concat for fused vmqke GEMM
__global__ void k_bcat(const float* __restrict__ a, const float* __restrict__ b,
                       const float* __restrict__ c, const float* __restrict__ d,
                       float* __restrict__ o)
{
    int i = blockIdx.x * 256 + threadIdx.x;
    if (i >= 1664) return;
    float v = (i < 512) ? a[i] : (i < 1024) ? b[i - 512] : (i < 1536) ? c[i - 1024] : d[i - 1536];
    o[i] = v;
}

// x (N x 512 fp32) -> XCAT left half (N x 1024 bf16)
__global__ void k_xcvt(const float* __restrict__ x, unsigned short* __restrict__ xcat)
{
    int g = blockIdx.x * 256 + threadIdx.x;
    int c = g & 511, r = g >> 9;
    xcat[(size_t)r * 1024 + c] = f2bf(x[g]);
}

// cos/sin of pos_phases -> bf16 tables
__global__ void k_phi(const float* __restrict__ pp, unsigned short* __restrict__ cphi,
                      unsigned short* __restrict__ sphi, int n)
{
    int i = blockIdx.x * 256 + threadIdx.x;
    if (i < n) {
        float p = pp[i];
        cphi[i] = f2bf(__cosf(p));
        sphi[i] = f2bf(__sinf(p));
    }
}

// ---------------------------------------------------------------------------
// fused g_lin + values: wave per row.
// ---------------------------------------------------------------------------
__global__ __launch_bounds__(256) void k_vg(const float* __restrict__ x,
                                            const float* __restrict__ wve,
                                            const float* __restrict__ bve,
                                            const float* __restrict__ wg,
                                            const float* __restrict__ bg,
                                            float* __restrict__ gv,
                                            float* __restrict__ glin)
{
    int wid = threadIdx.x >> 6, lane = threadIdx.x & 63;
    int row = blockIdx.x * 4 + wid;
    const float4* xr = (const float4*)(x + (size_t)row * DDIM);
    float4 a0 = xr[lane * 2], a1 = xr[lane * 2 + 1];
    float xs[8] = {a0.x, a0.y, a0.z, a0.w, a1.x, a1.y, a1.z, a1.w};
    float acc[8] = {0, 0, 0, 0, 0, 0, 0, 0};
    float accg = 0.f;
#pragma unroll
    for (int j = 0; j < 8; ++j) {
        int k = lane * 8 + j;
        const float4* wr = (const float4*)(wve + (size_t)k * 8);
        float4 w0 = wr[0], w1 = wr[1];
        acc[0] += xs[j] * w0.x; acc[1] += xs[j] * w0.y;
        acc[2] += xs[j] * w0.z; acc[3] += xs[j] * w0.w;
        acc[4] += xs[j] * w1.x; acc[5] += xs[j] * w1.y;
        acc[6] += xs[j] * w1.z; acc[7] += xs[j] * w1.w;
        accg += xs[j] * wg[k];
    }
#pragma unroll
    for (int off = 32; off >= 1; off >>= 1) {
#pragma unroll
        for (int m = 0; m < 8; ++m) acc[m] += __shfl_down(acc[m], off, 64);
        accg += __shfl_down(accg, off, 64);
    }
    if (lane == 0) {
        float gl = accg + bg[0];
        glin[row] = gl;
        float sg = sigmoid_(gl);
#pragma unroll
        for (int m = 0; m < 8; ++m) gv[(size_t)row * 8 + m] = (acc[m] + bve[m]) * sg;
    }
}

// ---------------------------------------------------------------------------
// scan family 1 (3 passes). bf16 v1/mlin/qlin, bf16 x (XCAT left), bf16 phi.
// ---------------------------------------------------------------------------
__global__ __launch_bounds__(256) void k_scan1a(
    const unsigned short* __restrict__ v1, const unsigned short* __restrict__ mlin,
    const unsigned short* __restrict__ xc,
    const unsigned short* __restrict__ cphi, const unsigned short* __restrict__ sphi,
    const float* __restrict__ msp, float* __restrict__ sum2)
{
    int g = blockIdx.x * 256 + threadIdx.x;   // B*NC2*D = 131072
    int d = g & 511;
    int rest = g >> 9;
    int chunk = rest & (NC2 - 1);
    int b = rest >> 6;
    float msabs = fabsf(msp[0]);
    size_t base = ((size_t)b * LSEQ + chunk * CL2) * DDIM + d;
    size_t xbase = ((size_t)b * LSEQ + chunk * CL2) * 1024 + d;
    size_t pbase = ((size_t)chunk * CL2) * DDIM + d;
    float ac = 0.f, as = 0.f, am = 0.f, ax = 0.f;
    for (int i = 0; i < CL2; ++i) {
        float ml = bf2f(mlin[base]), vv = bf2f(v1[base]), xv = bf2f(xc[xbase]);
        float cp = bf2f(cphi[pbase]), sp = bf2f(sphi[pbase]);
        float mag = msabs * sigmoid_(ml);
        float wv = mag * vv;
        ac += wv * cp; as += wv * sp; am += mag; ax += xv;
        base += DDIM; xbase += 1024; pbase += DDIM;
    }
    int col = (b * DDIM + d) * NC2 + chunk;
    sum2[0 * 131072 + col] = ac;
    sum2[1 * 131072 + col] = as;
    sum2[2 * 131072 + col] = am;
    sum2[3 * 131072 + col] = ax;
}

__global__ __launch_bounds__(256) void k_scan1b(float* __restrict__ sum2)
{
    int g = blockIdx.x * 256 + threadIdx.x;   // 8192 rows of NC2
    float* p = sum2 + (size_t)g * NC2;
    float run = 0.f;
    for (int i = 0; i < NC2; ++i) { float t = p[i]; p[i] = run; run += t; }
}

__global__ __launch_bounds__(256) void k_scan1c(
    const unsigned short* __restrict__ v1, const unsigned short* __restrict__ mlin,
    const unsigned short* __restrict__ qlin,
    const unsigned short* __restrict__ cphi, const unsigned short* __restrict__ sphi,
    const float* __restrict__ msp, const float* __restrict__ sum2,
    unsigned short* __restrict__ pret, unsigned short* __restrict__ xcat)
{
    int g = blockIdx.x * 256 + threadIdx.x;
    int d = g & 511;
    int rest = g >> 9;
    int chunk = rest & (NC2 - 1);
    int b = rest >> 6;
    float msabs = fabsf(msp[0]);
    int col = (b * DDIM + d) * NC2 + chunk;
    float ac = sum2[col];
    float as = sum2[131072 + col];
    float am = sum2[2 * 131072 + col];
    float ax = sum2[3 * 131072 + col];
    size_t base = ((size_t)b * LSEQ + chunk * CL2) * DDIM + d;
    size_t xbase = ((size_t)b * LSEQ + chunk * CL2) * 1024 + d;
    size_t pbase = ((size_t)chunk * CL2) * DDIM + d;
    int l = chunk * CL2;
    const float rsd = 0.04419417382415922f;   // 1/sqrt(512)
    for (int i = 0; i < CL2; ++i, ++l) {
        float ml = bf2f(mlin[base]), vv = bf2f(v1[base]), xv = bf2f(xcat[xbase]);
        float q = bf2f(qlin[base]);
        float cp = bf2f(cphi[pbase]), sp = bf2f(sphi[pbase]);
        float mag = msabs * sigmoid_(ml);
        float wv = mag * vv;
        ac += wv * cp; as += wv * sp; am += mag; ax += xv;
        float inv = rsqrtf(am + 1e-8f);
        float mc = ac * inv, msn = as * inv;
        float cq = __cosf(q), sq = __sinf(q);
        float cpq = cp * cq - sp * sq;
        float spq = sp * cq + cp * sq;
        pret[base] = f2bf((mc * cpq + msn * spq) * rsd);
        xcat[xbase + 512] = f2bf(ax / (float)(l + 1));
        base += DDIM; xbase += 1024; pbase += DDIM;
    }
}

// ---------------------------------------------------------------------------
// gate cumsum per batch
// ---------------------------------------------------------------------------
__global__ __launch_bounds__(1024) void k_gatescan(const float* __restrict__ glin,
                                                   float* __restrict__ gcum)
{
    __shared__ float s[1024];
    int b = blockIdx.x, tid = threadIdx.x;
    const float* gp = glin + (size_t)b * LSEQ + tid * 4;
    float e0 = sigmoid_(gp[0]);
    float e1 = sigmoid_(gp[1]);
    float e2 = sigmoid_(gp[2]);
    float e3 = sigmoid_(gp[3]);
    float l0 = e0, l1 = l0 + e1, l2 = l1 + e2, l3 = l2 + e3;
    s[tid] = l3;
    __syncthreads();
    for (int off = 1; off < 1024; off <<= 1) {
        float t = (tid >= off) ? s[tid - off] : 0.0f;
        __syncthreads();
        s[tid] += t;
        __syncthreads();
    }
    float excl = s[tid] - l3;
    float* out = gcum + (size_t)b * LSEQ + tid * 4;
    out[0] = excl + l0; out[1] = excl + l1; out[2] = excl + l2; out[3] = excl + l3;
}

// ---------------------------------------------------------------------------
// kv scan
// ---------------------------------------------------------------------------
__device__ __forceinline__ size_t kv_sum_idx(int b, int p, int v) {
    return ((((size_t)b * PDIM + p) * VDIM + v) * 2) * NC3;
}

__global__ __launch_bounds__(256) void k_kv1(const unsigned short* __restrict__ csp,
                                             const unsigned short* __restrict__ ssp,
                                             const float* __restrict__ gv,
                                             float* __restrict__ sum3)
{
    int blk = blockIdx.x;                 // B*NC3 = 512
    int chunk = blk & (NC3 - 1), b = blk >> 7;
    int tid = threadIdx.x;
    int w = tid >> 6, lane = tid & 63;
    int v = 2 * w + (lane & 1);
    int pq = lane >> 1;                   // 0..31
    float sc[4] = {0, 0, 0, 0}, ss[4] = {0, 0, 0, 0};
    const uint2* c2p = (const uint2*)csp;
    const uint2* s2p = (const uint2*)ssp;
    int t = b * LSEQ + chunk * CL3;
    for (int i = 0; i < CL3; ++i, ++t) {
        uint2 cu = c2p[(size_t)t * 32 + pq];
        uint2 su = s2p[(size_t)t * 32 + pq];
        float g = gv[(size_t)t * VDIM + v];
        sc[0] += bflo(cu.x) * g; sc[1] += bfhi(cu.x) * g;
        sc[2] += bflo(cu.y) * g; sc[3] += bfhi(cu.y) * g;
        ss[0] += bflo(su.x) * g; ss[1] += bfhi(su.x) * g;
        ss[2] += bflo(su.y) * g; ss[3] += bfhi(su.y) * g;
    }
#pragma unroll
    for (int j = 0; j < 4; ++j) {
        size_t base = kv_sum_idx(b, pq * 4 + j, v) + chunk;
        sum3[base] = sc[j];
        sum3[base + NC3] = ss[j];
    }
}

__global__ __launch_bounds__(256) void k_kv2(float* __restrict__ sum3)
{
    int g = blockIdx.x * 256 + threadIdx.x;   // 8192 rows
    float* p = sum3 + (size_t)g * NC3;
    float run = 0.f;
    for (int i = 0; i < NC3; ++i) { float t = p[i]; p[i] = run; run += t; }
}

__global__ __launch_bounds__(256) void k_kv3(const unsigned short* __restrict__ csp,
                                             const unsigned short* __restrict__ ssp,
                                             const unsigned short* __restrict__ cqp,
                                             const unsigned short* __restrict__ sqp,
                                             const float* __restrict__ gv,
                                             const float* __restrict__ gcum,
                                             const float* __restrict__ sum3,
                                             float* __restrict__ kvr)
{
    int blk = blockIdx.x;
    int chunk = blk & (NC3 - 1), b = blk >> 7;
    int tid = threadIdx.x;
    int w = tid >> 6, lane = tid & 63;
    int v = 2 * w + (lane & 1);
    int pq = lane >> 1;
    float sc[4], ss[4];
#pragma unroll
    for (int j = 0; j < 4; ++j) {
        size_t base = kv_sum_idx(b, pq * 4 + j, v) + chunk;
        sc[j] = sum3[base];
        ss[j] = sum3[base + NC3];
    }
    const uint2* c2p = (const uint2*)csp;
    const uint2* s2p = (const uint2*)ssp;
    const uint2* cq2p = (const uint2*)cqp;
    const uint2* sq2p = (const uint2*)sqp;
    const float rsp = 0.08838834764831845f;   // 1/sqrt(128)
    int t = b * LSEQ + chunk * CL3;
    for (int i = 0; i < CL3; ++i, ++t) {
        uint2 cu = c2p[(size_t)t * 32 + pq];
        uint2 su = s2p[(size_t)t * 32 + pq];
        float g = gv[(size_t)t * VDIM + v];
        sc[0] += bflo(cu.x) * g; sc[1] += bfhi(cu.x) * g;
        sc[2] += bflo(cu.y) * g; sc[3] += bfhi(cu.y) * g;
        ss[0] += bflo(su.x) * g; ss[1] += bfhi(su.x) * g;
        ss[2] += bflo(su.y) * g; ss[3] += bfhi(su.y) * g;
        uint2 qcu = cq2p[(size_t)t * 32 + pq];
        uint2 qsu = sq2p[(size_t)t * 32 + pq];
        float part = bflo(qcu.x) * sc[0] + bfhi(qcu.x) * sc[1]
                   + bflo(qcu.y) * sc[2] + bfhi(qcu.y) * sc[3]
                   + bflo(qsu.x) * ss[0] + bfhi(qsu.x) * ss[1]
                   + bflo(qsu.y) * ss[2] + bfhi(qsu.y) * ss[3];
        part += __shfl_down(part, 32, 64);
        part += __shfl_down(part, 16, 64);
        part += __shfl_down(part, 8, 64);
        part += __shfl_down(part, 4, 64);
        part += __shfl_down(part, 2, 64);
        if (lane < 2) {
            float gc = gcum[t];
            float scale = rsqrtf(fmaxf(gc, 1.0f)) * rsp;
            kvr[(size_t)t * VDIM + v] = part * scale;
        }
    }
}

// ---------------------------------------------------------------------------
// fused kv_out + LayerNorm. Wave per row; left lanes read comb (pos_out),
// right lanes compute kvr@w_kv on the fly (w_kv staged in LDS).
// ---------------------------------------------------------------------------
__global__ __launch_bounds__(256) void k_lnkv(unsigned short* __restrict__ comb,
                                              const float* __restrict__ kvr,
                                              const float* __restrict__ wkv,
                                              const float* __restrict__ bkv,
                                              const float* __restrict__ gam,
                                              const float* __restrict__ bet)
{
    __shared__ float wks[4096];
    __shared__ float bks[512];
    int tid = threadIdx.x;
    for (int i = tid; i < 4096; i += 256) wks[i] = wkv[i];
    for (int i = tid; i < 512; i += 256) bks[i] = bkv[i];
    __syncthreads();
    int wid = tid >> 6, lane = tid & 63;
    int row = blockIdx.x * 4 + wid;
    unsigned short* rp = comb + (size_t)row * 1024;
    float v[16];
    if (lane < 32) {
        uint4 u0 = *(uint4*)(rp + lane * 16);
        uint4 u1 = *(uint4*)(rp + lane * 16 + 8);
        unsigned int uu[8] = {u0.x, u0.y, u0.z, u0.w, u1.x, u1.y, u1.z, u1.w};
#pragma unroll
        for (int j = 0; j < 8; ++j) { v[2 * j] = bflo(uu[j]); v[2 * j + 1] = bfhi(uu[j]); }
    } else {
        int c0 = (lane - 32) * 16;
        const float4* kr = (const float4*)(kvr + (size_t)row * 8);
        float4 k0 = kr[0], k1 = kr[1];
        float kk[8] = {k0.x, k0.y, k0.z, k0.w, k1.x, k1.y, k1.z, k1.w};
#pragma unroll
        for (int j = 0; j < 16; ++j) {
            int c = c0 + j;
            float a = bks[c];
#pragma unroll
            for (int k = 0; k < 8; ++k) a += kk[k] * wks[k * 512 + c];
            v[j] = a;
        }
    }
    float s = 0.f, s2 = 0.f;
#pragma unroll
    for (int j = 0; j < 16; ++j) { s += v[j]; s2 += v[j] * v[j]; }
    for (int m = 32; m >= 1; m >>= 1) {
        s += __shfl_xor(s, m, 64);
        s2 += __shfl_xor(s2, m, 64);
    }
    float mu = s * (1.0f / 1024.0f);
    float var = s2 * (1.0f / 1024.0f) - mu * mu;
    float inv = rsqrtf(var + 1e-5f);
    int cbase = lane * 16;
    unsigned int ou[8];
#pragma unroll
    for (int j = 0; j < 8; ++j) {
        float g0 = gam[cbase + 2 * j], g1 = gam[cbase + 2 * j + 1];
        float b0 = bet[cbase + 2 * j], b1 = bet[cbase + 2 * j + 1];
        float o0 = (v[2 * j] - mu) * inv * g0 + b0;
        float o1 = (v[2 * j + 1] - mu) * inv * g1 + b1;
        ou[j] = (unsigned int)f2bf(o0) | ((unsigned int)f2bf(o1) << 16);
    }
    *(uint4*)(rp + cbase) = make_uint4(ou[0], ou[1], ou[2], ou[3]);
    *(uint4*)(rp + cbase + 8) = make_uint4(ou[4], ou[5], ou[6], ou[7]);
}

// ---------------------------------------------------------------------------
extern "C" void kernel_launch(void* const* d_in, const int* in_sizes, int n_in,
                              void* d_out, int out_size, void* d_ws, size_t ws_size,
                              hipStream_t stream)
{
    const float* x    = (const float*)d_in[0];
    const float* pp   = (const float*)d_in[1];
    const float* msp  = (const float*)d_in[2];
    const float* w_v  = (const float*)d_in[3];
    const float* b_v  = (const float*)d_in[4];
    const float* w_o  = (const float*)d_in[5];
    const float* b_o  = (const float*)d_in[6];
    const float* w_m  = (const float*)d_in[7];
    const float* b_m  = (const float*)d_in[8];
    const float* w_q  = (const float*)d_in[9];
    const float* b_q  = (const float*)d_in[10];
    const float* w_ke = (const float*)d_in[11];
    const float* b_ke = (const float*)d_in[12];
    const float* w_ve = (const float*)d_in[13];
    const float* b_ve = (const float*)d_in[14];
    const float* w_s1 = (const float*)d_in[15];
    const float* b_s1 = (const float*)d_in[16];
    const float* w_s2 = (const float*)d_in[17];
    const float* b_s2 = (const float*)d_in[18];
    const float* w_g  = (const float*)d_in[19];
    const float* b_g  = (const float*)d_in[20];
    const float* w_kv = (const float*)d_in[21];
    const float* b_kv = (const float*)d_in[22];
    const float* ln_g = (const float*)d_in[23];
    const float* ln_b = (const float*)d_in[24];
    const float* w_t1 = (const float*)d_in[25];
    const float* b_t1 = (const float*)d_in[26];
    const float* w_t2 = (const float*)d_in[27];
    const float* b_t2 = (const float*)d_in[28];
    float* out = (float*)d_out;
    float* ws = (float*)d_ws;
    (void)ws_size; (void)n_in; (void)in_sizes; (void)out_size;

    // ---- workspace layout (float offsets); ~157 MB
    unsigned short* V1bf   = (unsigned short*)(ws);              // N*512 bf16 (4M f)
    unsigned short* MLINbf = (unsigned short*)(ws + 4194304);    // N*512 bf16
    unsigned short* QLINbf = (unsigned short*)(ws + 8388608);    // N*512 bf16
    unsigned short* CQP    = (unsigned short*)(ws + 12582912);   // N*128 bf16 (1M f)
    unsigned short* SQP    = (unsigned short*)(ws + 13631488);
    unsigned short* CSP    = (unsigned short*)(ws + 14680064);
    unsigned short* SSP    = (unsigned short*)(ws + 15728640);
    unsigned short* HSbf   = (unsigned short*)(ws + 16777216);   // N*512 bf16
    unsigned short* PRETbf = (unsigned short*)(ws + 20971520);   // N*512 bf16
    unsigned short* CPHIbf = (unsigned short*)(ws + 25165824);   // L*512 bf16 (1M f)
    unsigned short* SPHIbf = (unsigned short*)(ws + 26214400);
    float* GVb   = ws + 27262976;                                // N*8
    float* GLINb = ws + 27394048;                                // N
    float* GCUMb = ws + 27410432;                                // N
    float* SUM2b = ws + 27426816;                                // 524288
    float* SUM3b = ws + 27951104;                                // 1048576
    float* KVRb  = ws + 28999680;                                // N*8
    unsigned short* XCAT   = (unsigned short*)(ws + 29130752);   // N*1024 bf16 (8M f)
    unsigned short* COMBbf = XCAT;                               // alias (x/ctx dead after s1)
    unsigned short* HTbf   = (unsigned short*)(ws);              // alias V1+MLIN (dead after scan1c)
    unsigned short* WtF    = (unsigned short*)(ws + 37519360);   // 1664x512 bf16
    unsigned short* ws1_t  = (unsigned short*)(ws + 37945344);   // 512x1024
    unsigned short* ws2_t  = (unsigned short*)(ws + 38207488);   // 128x512
    unsigned short* wo_t   = (unsigned short*)(ws + 38240256);   // 512x512
    unsigned short* wt1_t  = (unsigned short*)(ws + 38371328);   // 1024x1024
    unsigned short* wt2_t  = (unsigned short*)(ws + 38895616);   // 512x1024
    float* BIASF           = ws + 39157760;                      // 1664

    // 1. conversions + tables
    k_phi<<<8192, 256, 0, stream>>>(pp, CPHIbf, SPHIbf, 2097152);
    k_xcvt<<<32768, 256, 0, stream>>>(x, XCAT);
    k_bcat<<<7, 256, 0, stream>>>(b_v, b_m, b_q, b_ke, BIASF);
    k_wcvt<<<dim3(16, 16), 256, 0, stream>>>(w_v, 512, 512, WtF);
    k_wcvt<<<dim3(16, 16), 256, 0, stream>>>(w_m, 512, 512, WtF + 512 * 512);
    k_wcvt<<<dim3(16, 16), 256, 0, stream>>>(w_q, 512, 512, WtF + 1024 * 512);
    k_wcvt<<<dim3(4, 16), 256, 0, stream>>>(w_ke, 512, 128, WtF + 1536 * 512);
    k_wcvt<<<dim3(16, 32), 256, 0, stream>>>(w_s1, 1024, 512, ws1_t);
    k_wcvt<<<dim3(4, 16), 256, 0, stream>>>(w_s2, 512, 128, ws2_t);
    k_wcvt<<<dim3(16, 16), 256, 0, stream>>>(w_o, 512, 512, wo_t);
    k_wcvt<<<dim3(32, 32), 256, 0, stream>>>(w_t1, 1024, 1024, wt1_t);
    k_wcvt<<<dim3(16, 32), 256, 0, stream>>>(w_t2, 1024, 512, wt2_t);

    // 2. fused v/m/q/ke GEMM (+ query-phase epilogue) and small projections
    gemm_bf16<<<1664, 256, 0, stream>>>(XCAT, 1024, WtF, BIASF, 512, 13, 128, 2,
                                        V1bf, 512, 0, nullptr, nullptr,
                                        MLINbf, QLINbf, CQP, SQP);
    k_vg<<<4096, 256, 0, stream>>>(x, w_ve, b_ve, w_g, b_g, GVb, GLINb);

    // 3. (b,d) scans -> pos_ret, context_avg
    k_scan1a<<<512, 256, 0, stream>>>(V1bf, MLINbf, XCAT, CPHIbf, SPHIbf, msp, SUM2b);
    k_scan1b<<<32, 256, 0, stream>>>(SUM2b);
    k_scan1c<<<512, 256, 0, stream>>>(V1bf, MLINbf, QLINbf, CPHIbf, SPHIbf, msp, SUM2b, PRETbf, XCAT);

    // 4. storage-key branch: s1 -> gelu -> s2 -> storage phases (epilogue)
    gemm_bf16<<<512, 256, 0, stream>>>(XCAT, 1024, ws1_t, b_s1, 1024, 4, 128, 1,
                                       HSbf, 512, 0, nullptr, nullptr,
                                       nullptr, nullptr, nullptr, nullptr);
    gemm_bf16<<<128, 256, 0, stream>>>(HSbf, 512, ws2_t, b_s2, 512, 1, 128, 3,
                                       nullptr, 128, 0, nullptr, nullptr,
                                       nullptr, nullptr, CSP, SSP);
    k_gatescan<<<4, 1024, 0, stream>>>(GLINb, GCUMb);

    // 5. kv scan -> kv_retrieved
    k_kv1<<<512, 256, 0, stream>>>(CSP, SSP, GVb, SUM3b);
    k_kv2<<<32, 256, 0, stream>>>(SUM3b);
    k_kv3<<<512, 256, 0, stream>>>(CSP, SSP, CQP, SQP, GVb, GCUMb, SUM3b, KVRb);

    // 6. heads: o-GEMM into comb left; fused kvout+LN; MLP; residual out
    gemm_bf16<<<512, 256, 0, stream>>>(PRETbf, 512, wo_t, b_o, 512, 4, 128, 0,
                                       COMBbf, 1024, 0, nullptr, nullptr,
                                       nullptr, nullptr, nullptr, nullptr);
    k_lnkv<<<4096, 256, 0, stream>>>(COMBbf, KVRb, w_kv, b_kv, ln_g, ln_b);
    gemm_bf16<<<1024, 256, 0, stream>>>(COMBbf, 1024, wt1_t, b_t1, 1024, 8, 128, 1,
                                        HTbf, 1024, 0, nullptr, nullptr,
                                        nullptr, nullptr, nullptr, nullptr);
    gemm_bf16<<<512, 256, 0, stream>>>(HTbf, 1024, wt2_t, b_t2, 1024, 4, 128, 4,
                                       nullptr, 512, 0, out, x,
                                       nullptr, nullptr, nullptr, nullptr);
}